// Round 4
// baseline (60.959 us; speedup 1.0000x reference)
//
#include <hip/hip_runtime.h>

#define NB 10   // labels 1..10
#define BATCH 8
#define EPSF 1e-6f

constexpr int ELEMS_PER_BATCH = 128 * 128 * 128;        // 2,097,152
constexpr int VEC_PER_BATCH   = ELEMS_PER_BATCH / 4;    // 524,288 float4
constexpr int THREADS         = 256;
constexpr int VPT             = 8;                      // float4 loads per thread
constexpr int BLOCKS_PER_BATCH = VEC_PER_BATCH / (THREADS * VPT); // 256

// ws layout: accI[8][10], accX[8][10], accT[8][10] floats, then 8 uint presence masks
constexpr int WS_FLOATS = 3 * BATCH * NB;   // 240
constexpr int WS_BYTES  = WS_FLOATS * 4 + BATCH * 4;

// 4 waves/EU -> VGPR cap 128 (plenty for 30 acc + 3x12 prefetch regs), 16 waves/CU
__global__ __launch_bounds__(THREADS, 4)
void dice_partial(const float* __restrict__ x,
                  const float* __restrict__ t,
                  const int*   __restrict__ s,
                  float* __restrict__ acc)
{
    const int tid   = threadIdx.x;
    const int batch = blockIdx.y;
    const long long base = (long long)batch * VEC_PER_BATCH
                         + (long long)blockIdx.x * (THREADS * VPT);
    const float4* x4 = reinterpret_cast<const float4*>(x) + base;
    const float4* t4 = reinterpret_cast<const float4*>(t) + base;
    const int4*   s4 = reinterpret_cast<const int4*>(s)   + base;

    float aI[NB], aX[NB], aT[NB];
#pragma unroll
    for (int k = 0; k < NB; ++k) { aI[k] = 0.f; aX[k] = 0.f; aT[k] = 0.f; }
    unsigned bits = 0;   // bit v set <=> label value v seen

#define DO_ELEM(xe, te, se)                                     \
    do {                                                        \
        const float _x = (xe), _t = (te);                       \
        const int   _s = (se);                                  \
        const float _p = _x * _t;                               \
        bits |= (1u << _s);                                     \
        _Pragma("unroll")                                       \
        for (int k = 0; k < NB; ++k) {                          \
            const float m = (_s == k + 1) ? 1.0f : 0.0f;        \
            aI[k] = fmaf(m, _p, aI[k]);                         \
            aX[k] = fmaf(m, _x, aX[k]);                         \
            aT[k] = fmaf(m, _t, aT[k]);                         \
        }                                                       \
    } while (0)

    // depth-2 software pipeline: while computing iter i, loads for i+1, i+2 in flight
    float4 xa = x4[tid], ta = t4[tid];
    int4   sa = s4[tid];
    float4 xb = x4[THREADS + tid], tb = t4[THREADS + tid];
    int4   sb = s4[THREADS + tid];

#pragma unroll
    for (int i = 0; i < VPT; ++i) {
        float4 xc, tc; int4 sc;
        if (i + 2 < VPT) {                         // compile-time after unroll
            const int idx = (i + 2) * THREADS + tid;
            xc = x4[idx]; tc = t4[idx]; sc = s4[idx];
        }
        DO_ELEM(xa.x, ta.x, sa.x);
        DO_ELEM(xa.y, ta.y, sa.y);
        DO_ELEM(xa.z, ta.z, sa.z);
        DO_ELEM(xa.w, ta.w, sa.w);
        xa = xb; ta = tb; sa = sb;                 // register rotation (free)
        xb = xc; tb = tc; sb = sc;
    }
#undef DO_ELEM

    // wave-64 butterfly: every lane ends with the wave sum
#pragma unroll
    for (int k = 0; k < NB; ++k) {
#pragma unroll
        for (int off = 32; off > 0; off >>= 1) {
            aI[k] += __shfl_xor(aI[k], off);
            aX[k] += __shfl_xor(aX[k], off);
            aT[k] += __shfl_xor(aT[k], off);
        }
    }
#pragma unroll
    for (int off = 32; off > 0; off >>= 1)
        bits |= (unsigned)__shfl_xor((int)bits, off);

    // cross-wave combine in LDS (4 waves), then ~31 global atomics per block
    __shared__ float    wsum[4][32];
    __shared__ unsigned wb[4];
    const int wave = tid >> 6, lane = tid & 63;
    if (lane < NB) {
        wsum[wave][lane]          = aI[lane];
        wsum[wave][NB + lane]     = aX[lane];
        wsum[wave][2 * NB + lane] = aT[lane];
    }
    if (lane == 0) wb[wave] = bits;
    __syncthreads();

    if (tid < 3 * NB) {
        const float v = wsum[0][tid] + wsum[1][tid] + wsum[2][tid] + wsum[3][tid];
        const int which = tid / NB;          // 0:I 1:X 2:T
        const int lab   = tid % NB;
        atomicAdd(&acc[which * BATCH * NB + batch * NB + lab], v);
    }
    if (tid == 0) {
        const unsigned m = (wb[0] | wb[1] | wb[2] | wb[3]) >> 1;  // labels 1..10
        atomicOr((unsigned*)(acc + WS_FLOATS) + batch, m);
    }
}

__global__ void dice_final(const float* __restrict__ acc, float* __restrict__ out)
{
    const unsigned* pm = (const unsigned*)(acc + WS_FLOATS);
    unsigned mask = 0;
#pragma unroll
    for (int b = 0; b < BATCH; ++b) mask |= pm[b];

    const int k = threadIdx.x;
    float lpb = 0.0f, pres = 0.0f;
    if (k < NB) {
        const float* accI = acc;
        const float* accX = acc + BATCH * NB;
        const float* accT = acc + 2 * BATCH * NB;
        float sum_loss = 0.0f, valid = 0.0f;
        for (int b = 0; b < BATCH; ++b) {
            const float I = accI[b * NB + k];
            const float X = accX[b * NB + k];
            const float T = accT[b * NB + k];
            const float denom = X + T + 2.0f * EPSF;
            float bl = 1.0f - 2.0f * I / denom;
            if (T == 0.0f) bl = 0.0f; else valid += 1.0f;
            sum_loss += bl;
        }
        lpb  = sum_loss / fmaxf(valid, 1.0f);
        pres = ((mask >> k) & 1u) ? 1.0f : 0.0f;
    }
    float num = pres;
    float ls  = (pres > 0.0f) ? lpb : 0.0f;
    for (int off = 32; off > 0; off >>= 1) {
        num += __shfl_down(num, off);
        ls  += __shfl_down(ls,  off);
    }
    if (threadIdx.x == 0) {
        out[0] = ls / num;
        out[1] = 0.0f;
    }
}

extern "C" void kernel_launch(void* const* d_in, const int* in_sizes, int n_in,
                              void* d_out, int out_size, void* d_ws, size_t ws_size,
                              hipStream_t stream)
{
    const float* x = (const float*)d_in[0];
    const float* t = (const float*)d_in[1];
    const int*   s = (const int*)d_in[2];
    float* out = (float*)d_out;
    float* acc = (float*)d_ws;

    hipMemsetAsync(acc, 0, WS_BYTES, stream);

    dim3 grid(BLOCKS_PER_BATCH, BATCH);
    dice_partial<<<grid, THREADS, 0, stream>>>(x, t, s, acc);
    dice_final<<<1, 64, 0, stream>>>(acc, out);
}

// Round 5
// 48.351 us; speedup vs baseline: 1.2608x; 1.2608x over previous
//
#include <hip/hip_runtime.h>

#define NB 10   // labels 1..10
#define BATCH 8
#define EPSF 1e-6f

constexpr int ELEMS_PER_BATCH = 128 * 128 * 128;        // 2,097,152
constexpr int VEC_PER_BATCH   = ELEMS_PER_BATCH / 4;    // 524,288 float4
constexpr int THREADS         = 256;
constexpr int VPT             = 8;                      // float4 loads per thread per slice
constexpr int SLICE_VEC       = THREADS * VPT;          // 2048 float4 per slice
constexpr int BLOCKS_PER_BATCH = 64;                    // persistent: 4 slices per block
constexpr int SLICES_PER_BLOCK = VEC_PER_BATCH / (SLICE_VEC * BLOCKS_PER_BATCH); // 4
constexpr int GRID            = BLOCKS_PER_BATCH * BATCH;   // 512

// ws layout: accI[8][10], accX[8][10], accT[8][10] floats, then 8 uint presence masks
constexpr int WS_FLOATS = 3 * BATCH * NB;   // 240
constexpr int WS_BYTES  = WS_FLOATS * 4 + BATCH * 4;

// min 2 waves/EU -> VGPR cap 256: room for 96 load-dest regs + 30 accumulators
__global__ __launch_bounds__(THREADS, 2)
void dice_partial(const float* __restrict__ x,
                  const float* __restrict__ t,
                  const int*   __restrict__ s,
                  float* __restrict__ acc)
{
    const int tid   = threadIdx.x;
    const int batch = blockIdx.x >> 6;          // 64 blocks per batch
    const int sub   = blockIdx.x & 63;

    float aI[NB], aX[NB], aT[NB];
#pragma unroll
    for (int k = 0; k < NB; ++k) { aI[k] = 0.f; aX[k] = 0.f; aT[k] = 0.f; }
    unsigned bits = 0;   // bit v set <=> label value v seen

#define DO_ELEM(xe, te, se)                                     \
    do {                                                        \
        const float _x = (xe), _t = (te);                       \
        const int   _s = (se);                                  \
        const float _p = _x * _t;                               \
        bits |= (1u << _s);                                     \
        _Pragma("unroll")                                       \
        for (int k = 0; k < NB; ++k) {                          \
            const float m = (_s == k + 1) ? 1.0f : 0.0f;        \
            aI[k] = fmaf(m, _p, aI[k]);                         \
            aX[k] = fmaf(m, _x, aX[k]);                         \
            aT[k] = fmaf(m, _t, aT[k]);                         \
        }                                                       \
    } while (0)

    for (int j = 0; j < SLICES_PER_BLOCK; ++j) {
        const long long base = (long long)batch * VEC_PER_BATCH
                             + (long long)(sub + BLOCKS_PER_BATCH * j) * SLICE_VEC;
        const float4* x4 = reinterpret_cast<const float4*>(x) + base;
        const float4* t4 = reinterpret_cast<const float4*>(t) + base;
        const int4*   s4 = reinterpret_cast<const int4*>(s)   + base;

        // issue ALL 24 loads before any use: 24 KB in flight per wave (ILP hiding)
        float4 xv[VPT], tv[VPT]; int4 sv[VPT];
#pragma unroll
        for (int i = 0; i < VPT; ++i) {
            const int idx = i * THREADS + tid;   // coalesced, 16B/lane
            xv[i] = x4[idx];
            tv[i] = t4[idx];
            sv[i] = s4[idx];
        }
#pragma unroll
        for (int i = 0; i < VPT; ++i) {
            DO_ELEM(xv[i].x, tv[i].x, sv[i].x);
            DO_ELEM(xv[i].y, tv[i].y, sv[i].y);
            DO_ELEM(xv[i].z, tv[i].z, sv[i].z);
            DO_ELEM(xv[i].w, tv[i].w, sv[i].w);
        }
    }
#undef DO_ELEM

    // wave-64 butterfly: every lane ends with the wave sum (once per block now)
#pragma unroll
    for (int k = 0; k < NB; ++k) {
#pragma unroll
        for (int off = 32; off > 0; off >>= 1) {
            aI[k] += __shfl_xor(aI[k], off);
            aX[k] += __shfl_xor(aX[k], off);
            aT[k] += __shfl_xor(aT[k], off);
        }
    }
#pragma unroll
    for (int off = 32; off > 0; off >>= 1)
        bits |= (unsigned)__shfl_xor((int)bits, off);

    // cross-wave combine in LDS (4 waves), then ~31 global atomics per block
    __shared__ float    wsum[4][32];
    __shared__ unsigned wb[4];
    const int wave = tid >> 6, lane = tid & 63;
    if (lane < NB) {
        wsum[wave][lane]          = aI[lane];
        wsum[wave][NB + lane]     = aX[lane];
        wsum[wave][2 * NB + lane] = aT[lane];
    }
    if (lane == 0) wb[wave] = bits;
    __syncthreads();

    if (tid < 3 * NB) {
        const float v = wsum[0][tid] + wsum[1][tid] + wsum[2][tid] + wsum[3][tid];
        const int which = tid / NB;          // 0:I 1:X 2:T
        const int lab   = tid % NB;
        atomicAdd(&acc[which * BATCH * NB + batch * NB + lab], v);
    }
    if (tid == 0) {
        const unsigned m = (wb[0] | wb[1] | wb[2] | wb[3]) >> 1;  // labels 1..10
        atomicOr((unsigned*)(acc + WS_FLOATS) + batch, m);
    }
}

__global__ void dice_final(const float* __restrict__ acc, float* __restrict__ out)
{
    const unsigned* pm = (const unsigned*)(acc + WS_FLOATS);
    unsigned mask = 0;
#pragma unroll
    for (int b = 0; b < BATCH; ++b) mask |= pm[b];

    const int k = threadIdx.x;
    float lpb = 0.0f, pres = 0.0f;
    if (k < NB) {
        const float* accI = acc;
        const float* accX = acc + BATCH * NB;
        const float* accT = acc + 2 * BATCH * NB;
        float sum_loss = 0.0f, valid = 0.0f;
        for (int b = 0; b < BATCH; ++b) {
            const float I = accI[b * NB + k];
            const float X = accX[b * NB + k];
            const float T = accT[b * NB + k];
            const float denom = X + T + 2.0f * EPSF;
            float bl = 1.0f - 2.0f * I / denom;
            if (T == 0.0f) bl = 0.0f; else valid += 1.0f;
            sum_loss += bl;
        }
        lpb  = sum_loss / fmaxf(valid, 1.0f);
        pres = ((mask >> k) & 1u) ? 1.0f : 0.0f;
    }
    float num = pres;
    float ls  = (pres > 0.0f) ? lpb : 0.0f;
    for (int off = 32; off > 0; off >>= 1) {
        num += __shfl_down(num, off);
        ls  += __shfl_down(ls,  off);
    }
    if (threadIdx.x == 0) {
        out[0] = ls / num;
        out[1] = 0.0f;
    }
}

extern "C" void kernel_launch(void* const* d_in, const int* in_sizes, int n_in,
                              void* d_out, int out_size, void* d_ws, size_t ws_size,
                              hipStream_t stream)
{
    const float* x = (const float*)d_in[0];
    const float* t = (const float*)d_in[1];
    const int*   s = (const int*)d_in[2];
    float* out = (float*)d_out;
    float* acc = (float*)d_ws;

    hipMemsetAsync(acc, 0, WS_BYTES, stream);

    dice_partial<<<GRID, THREADS, 0, stream>>>(x, t, s, acc);
    dice_final<<<1, 64, 0, stream>>>(acc, out);
}

// Round 6
// 48.114 us; speedup vs baseline: 1.2670x; 1.0049x over previous
//
#include <hip/hip_runtime.h>

#define NB 10   // labels 1..10
#define BATCH 8
#define EPSF 1e-6f

constexpr int ELEMS_PER_BATCH = 128 * 128 * 128;        // 2,097,152
constexpr int VEC_PER_BATCH   = ELEMS_PER_BATCH / 4;    // 524,288 float4
constexpr int THREADS         = 256;
constexpr int VPT             = 8;                      // float4 loads per thread per slice
constexpr int SLICE_VEC       = THREADS * VPT;          // 2048 float4 per slice
constexpr int BLOCKS_PER_BATCH = 128;
constexpr int SLICES_PER_BLOCK = VEC_PER_BATCH / (SLICE_VEC * BLOCKS_PER_BATCH); // 2
constexpr int GRID            = BLOCKS_PER_BATCH * BATCH;   // 1024

// ws: one 32-float record per block: [0..9]=I, [10..19]=X, [20..29]=T, [30]=mask(uint)
// every slot written unconditionally every call -> no zeroing needed.
constexpr int REC = 32;

// 4 waves/EU -> VGPR cap 128: ~24 in-flight float4 + 30 accumulators fit
__global__ __launch_bounds__(THREADS, 4)
void dice_partial(const float* __restrict__ x,
                  const float* __restrict__ t,
                  const int*   __restrict__ s,
                  float* __restrict__ ws)
{
    const int tid   = threadIdx.x;
    const int batch = blockIdx.x >> 7;          // 128 blocks per batch
    const int sub   = blockIdx.x & 127;

    float aI[NB], aX[NB], aT[NB];
#pragma unroll
    for (int k = 0; k < NB; ++k) { aI[k] = 0.f; aX[k] = 0.f; aT[k] = 0.f; }
    unsigned bits = 0;   // bit v set <=> label value v seen

#define DO_ELEM(xe, te, se)                                     \
    do {                                                        \
        const float _x = (xe), _t = (te);                       \
        const int   _s = (se);                                  \
        const float _p = _x * _t;                               \
        bits |= (1u << _s);                                     \
        _Pragma("unroll")                                       \
        for (int k = 0; k < NB; ++k) {                          \
            const float m = (_s == k + 1) ? 1.0f : 0.0f;        \
            aI[k] = fmaf(m, _p, aI[k]);                         \
            aX[k] = fmaf(m, _x, aX[k]);                         \
            aT[k] = fmaf(m, _t, aT[k]);                         \
        }                                                       \
    } while (0)

#pragma unroll
    for (int j = 0; j < SLICES_PER_BLOCK; ++j) {
        const long long base = (long long)batch * VEC_PER_BATCH
                             + (long long)(sub + BLOCKS_PER_BATCH * j) * SLICE_VEC;
        const float4* x4 = reinterpret_cast<const float4*>(x) + base;
        const float4* t4 = reinterpret_cast<const float4*>(t) + base;
        const int4*   s4 = reinterpret_cast<const int4*>(s)   + base;

        // issue ALL 24 loads before any use (ILP latency hiding)
        float4 xv[VPT], tv[VPT]; int4 sv[VPT];
#pragma unroll
        for (int i = 0; i < VPT; ++i) {
            const int idx = i * THREADS + tid;   // coalesced, 16B/lane
            xv[i] = x4[idx];
            tv[i] = t4[idx];
            sv[i] = s4[idx];
        }
#pragma unroll
        for (int i = 0; i < VPT; ++i) {
            DO_ELEM(xv[i].x, tv[i].x, sv[i].x);
            DO_ELEM(xv[i].y, tv[i].y, sv[i].y);
            DO_ELEM(xv[i].z, tv[i].z, sv[i].z);
            DO_ELEM(xv[i].w, tv[i].w, sv[i].w);
        }
    }
#undef DO_ELEM

    // wave-64 butterfly (once per block)
#pragma unroll
    for (int k = 0; k < NB; ++k) {
#pragma unroll
        for (int off = 32; off > 0; off >>= 1) {
            aI[k] += __shfl_xor(aI[k], off);
            aX[k] += __shfl_xor(aX[k], off);
            aT[k] += __shfl_xor(aT[k], off);
        }
    }
#pragma unroll
    for (int off = 32; off > 0; off >>= 1)
        bits |= (unsigned)__shfl_xor((int)bits, off);

    // cross-wave combine in LDS, then PLAIN stores to this block's private record
    __shared__ float    wsum[4][32];
    __shared__ unsigned wb[4];
    const int wave = tid >> 6, lane = tid & 63;
    if (lane < NB) {
        wsum[wave][lane]          = aI[lane];
        wsum[wave][NB + lane]     = aX[lane];
        wsum[wave][2 * NB + lane] = aT[lane];
    }
    if (lane == 0) wb[wave] = bits;
    __syncthreads();

    if (tid < 3 * NB) {
        const float v = wsum[0][tid] + wsum[1][tid] + wsum[2][tid] + wsum[3][tid];
        ws[blockIdx.x * REC + tid] = v;
    }
    if (tid == 0)
        ((unsigned*)ws)[blockIdx.x * REC + 30] = wb[0] | wb[1] | wb[2] | wb[3];
}

__global__ void dice_final(const float* __restrict__ ws, float* __restrict__ out)
{
    const int tid = threadIdx.x;
    __shared__ float    sAll[BATCH][3 * NB];   // summed I/X/T per batch
    __shared__ unsigned um[THREADS];

    // phase 1: 240 combos (batch, which*10+lab) each sum 128 block records
    if (tid < BATCH * 3 * NB) {
        const int batch = tid / (3 * NB);
        const int idx   = tid % (3 * NB);
        float v = 0.0f;
        for (int j = 0; j < BLOCKS_PER_BATCH; ++j)
            v += ws[(batch * BLOCKS_PER_BATCH + j) * REC + idx];
        sAll[batch][idx] = v;
    }

    // phase 2: OR all presence masks
    unsigned m = 0;
#pragma unroll
    for (int j = 0; j < GRID / THREADS; ++j)
        m |= ((const unsigned*)ws)[(tid * (GRID / THREADS) + j) * REC + 30];
    um[tid] = m;
    __syncthreads();
    for (int st = THREADS / 2; st > 0; st >>= 1) {
        if (tid < st) um[tid] |= um[tid + st];
        __syncthreads();
    }
    const unsigned mask = um[0];   // bit v = label value v present (v=1..10)

    // phase 3: dice per label, then reduce over labels (first wave only)
    if (tid < 64) {
        float lpb = 0.0f, pres = 0.0f;
        if (tid < NB) {
            float sum_loss = 0.0f, valid = 0.0f;
            for (int b = 0; b < BATCH; ++b) {
                const float I = sAll[b][tid];
                const float X = sAll[b][NB + tid];
                const float T = sAll[b][2 * NB + tid];
                const float denom = X + T + 2.0f * EPSF;
                float bl = 1.0f - 2.0f * I / denom;
                if (T == 0.0f) bl = 0.0f; else valid += 1.0f;
                sum_loss += bl;
            }
            lpb  = sum_loss / fmaxf(valid, 1.0f);
            pres = ((mask >> (tid + 1)) & 1u) ? 1.0f : 0.0f;
        }
        float num = pres;
        float ls  = (pres > 0.0f) ? lpb : 0.0f;
#pragma unroll
        for (int off = 32; off > 0; off >>= 1) {
            num += __shfl_down(num, off);
            ls  += __shfl_down(ls,  off);
        }
        if (tid == 0) {
            out[0] = ls / num;
            out[1] = 0.0f;
        }
    }
}

extern "C" void kernel_launch(void* const* d_in, const int* in_sizes, int n_in,
                              void* d_out, int out_size, void* d_ws, size_t ws_size,
                              hipStream_t stream)
{
    const float* x = (const float*)d_in[0];
    const float* t = (const float*)d_in[1];
    const int*   s = (const int*)d_in[2];
    float* out = (float*)d_out;
    float* ws  = (float*)d_ws;

    dice_partial<<<GRID, THREADS, 0, stream>>>(x, t, s, ws);
    dice_final<<<1, THREADS, 0, stream>>>(ws, out);
}